// Round 4
// baseline (239.273 us; speedup 1.0000x reference)
//
#include <hip/hip_runtime.h>
#include <math.h>

#define NB 32
#define NT 4096
#define ND 512
#define NA 64
#define NCHUNK 16          // t-chunks for context partials
#define TCHUNK (NT / NCHUNK)

// ---------------------------------------------------------------- scores ----
// scores[b,t] = w2 . tanh(W1 @ x[b,t] + b1)
// Register-blocked GEMM. Block = 256 threads computes 256 (b,t)-rows x 64 a.
// Thread tile 8 rows x 8 a-cols. W1 staged in DOUBLE-BUFFERED LDS K-chunks.
// __launch_bounds__(256,2): min 2 waves/EU -> VGPR cap 256. R3's default
// heuristic capped at 96 VGPR and spilled ~35 MB/dispatch to scratch
// (WRITE_SIZE evidence); this tile needs ~115-190 live regs.
#define SB 256             // threads per block
#define ROWS_PB 256        // rows per block -> 512 blocks
#define KC 64              // k-chunk in floats
#define KC4 (KC / 4)       // 16 float4 per a-row
#define NKCH (ND / KC)     // 8 chunks
#define STG ((NA * KC4) / SB)   // 4 staging float4 per thread per chunk

__global__ __launch_bounds__(SB, 2) void k_scores(
    const float* __restrict__ x, const float* __restrict__ W1,
    const float* __restrict__ b1, const float* __restrict__ w2,
    float* __restrict__ scores)
{
    __shared__ float4 w_lds[2][NA * KC4];      // 2 x 16 KB

    const int tid  = threadIdx.x;
    const int ag   = tid & 7;                  // a-group: cols ag*8 .. +7
    const int rgrp = tid >> 3;                 // 32 row-groups x 8 rows
    const size_t row0 = (size_t)blockIdx.x * ROWS_PB + (size_t)rgrp * 8;

    const float4* __restrict__ x4 = reinterpret_cast<const float4*>(x);
    const float4* __restrict__ W4 = reinterpret_cast<const float4*>(W1);

    // stage chunk 0 -> buffer 0 (value for (a,kq) stored at col kq^(a>>3))
#pragma unroll
    for (int r = 0; r < STG; ++r) {
        int i  = r * SB + tid;
        int a  = i >> 4;                       // / KC4
        int kq = i & (KC4 - 1);
        w_lds[0][a * KC4 + (kq ^ (a >> 3))] = W4[a * (ND / 4) + kq];
    }

    float acc[8][8];
#pragma unroll
    for (int i = 0; i < 8; ++i)
#pragma unroll
        for (int j = 0; j < 8; ++j) acc[i][j] = 0.f;

    for (int c = 0; c < NKCH; ++c) {
        __syncthreads();                       // staged chunk c visible

        // issue next chunk's global loads early (latency hides under FMAs)
        float4 nxt[STG];
        if (c + 1 < NKCH) {
#pragma unroll
            for (int r = 0; r < STG; ++r) {
                int i  = r * SB + tid;
                int a  = i >> 4;
                int kq = i & (KC4 - 1);
                nxt[r] = W4[a * (ND / 4) + (c + 1) * KC4 + kq];
            }
        }

        const float4* __restrict__ wl = w_lds[c & 1];
        const size_t xb = (size_t)c * KC4;

        // per-row chunk base pointers: inner loop folds dq into imm offsets
        const float4* xp[8];
#pragma unroll
        for (int i = 0; i < 8; ++i)
            xp[i] = x4 + (row0 + i) * (ND / 4) + xb;

        for (int dq = 0; dq < KC4; ++dq) {
            float4 xv[8];
#pragma unroll
            for (int i = 0; i < 8; ++i)
                xv[i] = xp[i][dq];
            const int dsw = dq ^ ag;           // un-swizzle: a>>3 == ag here
            float4 wv[8];
#pragma unroll
            for (int j = 0; j < 8; ++j)
                wv[j] = wl[(ag * 8 + j) * KC4 + dsw];
#pragma unroll
            for (int i = 0; i < 8; ++i)
#pragma unroll
                for (int j = 0; j < 8; ++j) {
                    acc[i][j] = fmaf(xv[i].x, wv[j].x, acc[i][j]);
                    acc[i][j] = fmaf(xv[i].y, wv[j].y, acc[i][j]);
                    acc[i][j] = fmaf(xv[i].z, wv[j].z, acc[i][j]);
                    acc[i][j] = fmaf(xv[i].w, wv[j].w, acc[i][j]);
                }
        }

        // write next chunk into the OTHER buffer (no WAR hazard possible)
        if (c + 1 < NKCH) {
            float4* __restrict__ wld = w_lds[(c + 1) & 1];
#pragma unroll
            for (int r = 0; r < STG; ++r) {
                int i  = r * SB + tid;
                int a  = i >> 4;
                int kq = i & (KC4 - 1);
                wld[a * KC4 + (kq ^ (a >> 3))] = nxt[r];
            }
        }
    }

    // epilogue: p_i = sum_j w2[ag*8+j] * tanh(acc[i][j] + b1[ag*8+j])
    float b1v[8], w2v[8];
#pragma unroll
    for (int j = 0; j < 8; ++j) {
        b1v[j] = b1[ag * 8 + j];
        w2v[j] = w2[ag * 8 + j];
    }
    float p[8];
#pragma unroll
    for (int i = 0; i < 8; ++i) {
        float s = 0.f;
#pragma unroll
        for (int j = 0; j < 8; ++j)
            s += w2v[j] * tanhf(acc[i][j] + b1v[j]);
        p[i] = s;
    }
#pragma unroll
    for (int off = 1; off < 8; off <<= 1)
#pragma unroll
        for (int i = 0; i < 8; ++i) p[i] += __shfl_xor(p[i], off);

    if (ag == 0) {
#pragma unroll
        for (int i = 0; i < 8; ++i) scores[row0 + i] = p[i];
    }
}

// --------------------------------------------------------------- softmax ----
__global__ __launch_bounds__(256) void k_softmax(
    const float* __restrict__ scores, const int* __restrict__ mask,
    float* __restrict__ weights)
{
    __shared__ float e_lds[NT];    // 16 KB
    __shared__ float red[4];

    int b = blockIdx.x;
    const float* srow = scores + (size_t)b * NT;
    const int*   mrow = mask   + (size_t)b * NT;

    float m = -INFINITY;
    for (int i = 0; i < NT / 256; ++i) {
        int t = i * 256 + threadIdx.x;
        float s = srow[t];
        bool valid = (mrow[t] != 0);
        e_lds[t] = valid ? s : -INFINITY;
        if (valid) m = fmaxf(m, s);
    }
#pragma unroll
    for (int off = 32; off; off >>= 1) m = fmaxf(m, __shfl_xor(m, off));
    if ((threadIdx.x & 63) == 0) red[threadIdx.x >> 6] = m;
    __syncthreads();
    m = fmaxf(fmaxf(red[0], red[1]), fmaxf(red[2], red[3]));
    __syncthreads();

    float sum = 0.f;
    for (int i = 0; i < NT / 256; ++i) {
        int t = i * 256 + threadIdx.x;
        float e = expf(e_lds[t] - m);
        e_lds[t] = e;
        sum += e;
    }
#pragma unroll
    for (int off = 32; off; off >>= 1) sum += __shfl_xor(sum, off);
    if ((threadIdx.x & 63) == 0) red[threadIdx.x >> 6] = sum;
    __syncthreads();
    float total = (red[0] + red[1]) + (red[2] + red[3]);
    float inv = 1.f / total;

    for (int i = 0; i < NT / 256; ++i) {
        int t = i * 256 + threadIdx.x;
        weights[(size_t)b * NT + t] = e_lds[t] * inv;
    }
}

// ------------------------------------------------------- context partials ---
__global__ __launch_bounds__(512) void k_ctx_partial(
    const float* __restrict__ x, const float* __restrict__ weights,
    float* __restrict__ partials)
{
    int b = blockIdx.x >> 4;
    int c = blockIdx.x & (NCHUNK - 1);
    int d = threadIdx.x;

    const float* xp = x + ((size_t)b * NT + (size_t)c * TCHUNK) * ND + d;
    const float* wp = weights + (size_t)b * NT + (size_t)c * TCHUNK;

    float acc = 0.f;
#pragma unroll 4
    for (int t = 0; t < TCHUNK; ++t)
        acc = fmaf(wp[t], xp[(size_t)t * ND], acc);

    partials[(size_t)blockIdx.x * ND + d] = acc;
}

// -------------------------------------------------------- context reduce ----
__global__ __launch_bounds__(256) void k_ctx_reduce(
    const float* __restrict__ partials, float* __restrict__ ctx)
{
    int i = blockIdx.x * 256 + threadIdx.x;   // b*ND + d
    int b = i >> 9;
    int d = i & (ND - 1);
    float s = 0.f;
#pragma unroll
    for (int c = 0; c < NCHUNK; ++c)
        s += partials[((size_t)(b * NCHUNK + c)) * ND + d];
    ctx[i] = s;
}

// ------------------------------------------------------------------ launch --
extern "C" void kernel_launch(void* const* d_in, const int* in_sizes, int n_in,
                              void* d_out, int out_size, void* d_ws, size_t ws_size,
                              hipStream_t stream)
{
    const float* x    = (const float*)d_in[0];
    const int*   mask = (const int*)d_in[1];
    const float* W1   = (const float*)d_in[2];
    const float* b1   = (const float*)d_in[3];
    const float* w2   = (const float*)d_in[4];

    float* ctx     = (float*)d_out;                  // B*D
    float* weights = (float*)d_out + NB * ND;        // B*T
    float* scores   = (float*)d_ws;                  // B*T
    float* partials = (float*)d_ws + NB * NT;        // B*NCHUNK*D

    k_scores<<<(NB * NT) / ROWS_PB, SB, 0, stream>>>(x, W1, b1, w2, scores);
    k_softmax<<<NB, 256, 0, stream>>>(scores, mask, weights);
    k_ctx_partial<<<NB * NCHUNK, 512, 0, stream>>>(x, weights, partials);
    k_ctx_reduce<<<NB * ND / 256, 256, 0, stream>>>(partials, ctx);
}

// Round 5
// 230.974 us; speedup vs baseline: 1.0359x; 1.0359x over previous
//
#include <hip/hip_runtime.h>
#include <math.h>

#define NB 32
#define NT 4096
#define ND 512
#define NA 64
#define NCHUNK 16          // t-chunks for context partials
#define TCHUNK (NT / NCHUNK)

// ---------------------------------------------------------------- scores ----
// scores[b,t] = w2 . tanh(W1 @ x[b,t] + b1)
// Register-blocked GEMM. Block = 256 threads computes 256 (b,t)-rows x 64 a.
// Thread tile 8 rows x 8 a-cols. W1 staged in DOUBLE-BUFFERED LDS K-chunks.
// amdgpu_waves_per_eu(2,2): grid is 512 blocks = 2 blocks/CU = 8 waves/CU
// = 2 waves/EU — occupancy is GRID-capped, so pin the register allocator
// to that occupancy (256-VGPR budget). R3/R4 evidence: default heuristic
// chose 96/80 VGPR chasing unreachable occupancy and spilled ~35-80 MB
// to scratch per dispatch (FETCH 470MB vs 268MB ideal, VALUBusy 38%).
#define SB 256             // threads per block
#define ROWS_PB 256        // rows per block -> 512 blocks
#define KC 64              // k-chunk in floats
#define KC4 (KC / 4)       // 16 float4 per a-row
#define NKCH (ND / KC)     // 8 chunks
#define STG ((NA * KC4) / SB)   // 4 staging float4 per thread per chunk

__global__ void __launch_bounds__(SB)
__attribute__((amdgpu_waves_per_eu(2, 2)))
k_scores(
    const float* __restrict__ x, const float* __restrict__ W1,
    const float* __restrict__ b1, const float* __restrict__ w2,
    float* __restrict__ scores)
{
    __shared__ float4 w_lds[2][NA * KC4];      // 2 x 16 KB

    const int tid  = threadIdx.x;
    const int ag   = tid & 7;                  // a-group: cols ag*8 .. +7
    const int rgrp = tid >> 3;                 // 32 row-groups x 8 rows
    const size_t row0 = (size_t)blockIdx.x * ROWS_PB + (size_t)rgrp * 8;

    const float4* __restrict__ x4 = reinterpret_cast<const float4*>(x);
    const float4* __restrict__ W4 = reinterpret_cast<const float4*>(W1);

    // stage chunk 0 -> buffer 0 (value for (a,kq) stored at col kq^(a>>3))
#pragma unroll
    for (int r = 0; r < STG; ++r) {
        int i  = r * SB + tid;
        int a  = i >> 4;                       // / KC4
        int kq = i & (KC4 - 1);
        w_lds[0][a * KC4 + (kq ^ (a >> 3))] = W4[a * (ND / 4) + kq];
    }

    float acc[8][8];
#pragma unroll
    for (int i = 0; i < 8; ++i)
#pragma unroll
        for (int j = 0; j < 8; ++j) acc[i][j] = 0.f;

    for (int c = 0; c < NKCH; ++c) {
        __syncthreads();                       // staged chunk c visible

        // issue next chunk's global loads early (latency hides under FMAs)
        float4 nxt[STG];
        if (c + 1 < NKCH) {
#pragma unroll
            for (int r = 0; r < STG; ++r) {
                int i  = r * SB + tid;
                int a  = i >> 4;
                int kq = i & (KC4 - 1);
                nxt[r] = W4[a * (ND / 4) + (c + 1) * KC4 + kq];
            }
        }

        const float4* __restrict__ wl = w_lds[c & 1];
        const size_t xb = (size_t)c * KC4;

        // per-row chunk base pointers: inner loop folds dq into imm offsets
        const float4* xp[8];
#pragma unroll
        for (int i = 0; i < 8; ++i)
            xp[i] = x4 + (row0 + i) * (ND / 4) + xb;

        for (int dq = 0; dq < KC4; ++dq) {
            float4 xv[8];
#pragma unroll
            for (int i = 0; i < 8; ++i)
                xv[i] = xp[i][dq];
            const int dsw = dq ^ ag;           // un-swizzle: a>>3 == ag here
            float4 wv[8];
#pragma unroll
            for (int j = 0; j < 8; ++j)
                wv[j] = wl[(ag * 8 + j) * KC4 + dsw];
#pragma unroll
            for (int i = 0; i < 8; ++i)
#pragma unroll
                for (int j = 0; j < 8; ++j) {
                    acc[i][j] = fmaf(xv[i].x, wv[j].x, acc[i][j]);
                    acc[i][j] = fmaf(xv[i].y, wv[j].y, acc[i][j]);
                    acc[i][j] = fmaf(xv[i].z, wv[j].z, acc[i][j]);
                    acc[i][j] = fmaf(xv[i].w, wv[j].w, acc[i][j]);
                }
        }

        // write next chunk into the OTHER buffer (no WAR hazard possible)
        if (c + 1 < NKCH) {
            float4* __restrict__ wld = w_lds[(c + 1) & 1];
#pragma unroll
            for (int r = 0; r < STG; ++r) {
                int i  = r * SB + tid;
                int a  = i >> 4;
                int kq = i & (KC4 - 1);
                wld[a * KC4 + (kq ^ (a >> 3))] = nxt[r];
            }
        }
    }

    // epilogue: p_i = sum_j w2[ag*8+j] * tanh(acc[i][j] + b1[ag*8+j])
    float b1v[8], w2v[8];
#pragma unroll
    for (int j = 0; j < 8; ++j) {
        b1v[j] = b1[ag * 8 + j];
        w2v[j] = w2[ag * 8 + j];
    }
    float p[8];
#pragma unroll
    for (int i = 0; i < 8; ++i) {
        float s = 0.f;
#pragma unroll
        for (int j = 0; j < 8; ++j)
            s += w2v[j] * tanhf(acc[i][j] + b1v[j]);
        p[i] = s;
    }
#pragma unroll
    for (int off = 1; off < 8; off <<= 1)
#pragma unroll
        for (int i = 0; i < 8; ++i) p[i] += __shfl_xor(p[i], off);

    if (ag == 0) {
#pragma unroll
        for (int i = 0; i < 8; ++i) scores[row0 + i] = p[i];
    }
}

// --------------------------------------------------------------- softmax ----
__global__ __launch_bounds__(256) void k_softmax(
    const float* __restrict__ scores, const int* __restrict__ mask,
    float* __restrict__ weights)
{
    __shared__ float e_lds[NT];    // 16 KB
    __shared__ float red[4];

    int b = blockIdx.x;
    const float* srow = scores + (size_t)b * NT;
    const int*   mrow = mask   + (size_t)b * NT;

    float m = -INFINITY;
    for (int i = 0; i < NT / 256; ++i) {
        int t = i * 256 + threadIdx.x;
        float s = srow[t];
        bool valid = (mrow[t] != 0);
        e_lds[t] = valid ? s : -INFINITY;
        if (valid) m = fmaxf(m, s);
    }
#pragma unroll
    for (int off = 32; off; off >>= 1) m = fmaxf(m, __shfl_xor(m, off));
    if ((threadIdx.x & 63) == 0) red[threadIdx.x >> 6] = m;
    __syncthreads();
    m = fmaxf(fmaxf(red[0], red[1]), fmaxf(red[2], red[3]));
    __syncthreads();

    float sum = 0.f;
    for (int i = 0; i < NT / 256; ++i) {
        int t = i * 256 + threadIdx.x;
        float e = expf(e_lds[t] - m);
        e_lds[t] = e;
        sum += e;
    }
#pragma unroll
    for (int off = 32; off; off >>= 1) sum += __shfl_xor(sum, off);
    if ((threadIdx.x & 63) == 0) red[threadIdx.x >> 6] = sum;
    __syncthreads();
    float total = (red[0] + red[1]) + (red[2] + red[3]);
    float inv = 1.f / total;

    for (int i = 0; i < NT / 256; ++i) {
        int t = i * 256 + threadIdx.x;
        weights[(size_t)b * NT + t] = e_lds[t] * inv;
    }
}

// ------------------------------------------------------- context partials ---
__global__ __launch_bounds__(512) void k_ctx_partial(
    const float* __restrict__ x, const float* __restrict__ weights,
    float* __restrict__ partials)
{
    int b = blockIdx.x >> 4;
    int c = blockIdx.x & (NCHUNK - 1);
    int d = threadIdx.x;

    const float* xp = x + ((size_t)b * NT + (size_t)c * TCHUNK) * ND + d;
    const float* wp = weights + (size_t)b * NT + (size_t)c * TCHUNK;

    float acc = 0.f;
#pragma unroll 4
    for (int t = 0; t < TCHUNK; ++t)
        acc = fmaf(wp[t], xp[(size_t)t * ND], acc);

    partials[(size_t)blockIdx.x * ND + d] = acc;
}

// -------------------------------------------------------- context reduce ----
__global__ __launch_bounds__(256) void k_ctx_reduce(
    const float* __restrict__ partials, float* __restrict__ ctx)
{
    int i = blockIdx.x * 256 + threadIdx.x;   // b*ND + d
    int b = i >> 9;
    int d = i & (ND - 1);
    float s = 0.f;
#pragma unroll
    for (int c = 0; c < NCHUNK; ++c)
        s += partials[((size_t)(b * NCHUNK + c)) * ND + d];
    ctx[i] = s;
}

// ------------------------------------------------------------------ launch --
extern "C" void kernel_launch(void* const* d_in, const int* in_sizes, int n_in,
                              void* d_out, int out_size, void* d_ws, size_t ws_size,
                              hipStream_t stream)
{
    const float* x    = (const float*)d_in[0];
    const int*   mask = (const int*)d_in[1];
    const float* W1   = (const float*)d_in[2];
    const float* b1   = (const float*)d_in[3];
    const float* w2   = (const float*)d_in[4];

    float* ctx     = (float*)d_out;                  // B*D
    float* weights = (float*)d_out + NB * ND;        // B*T
    float* scores   = (float*)d_ws;                  // B*T
    float* partials = (float*)d_ws + NB * NT;        // B*NCHUNK*D

    k_scores<<<(NB * NT) / ROWS_PB, SB, 0, stream>>>(x, W1, b1, w2, scores);
    k_softmax<<<NB, 256, 0, stream>>>(scores, mask, weights);
    k_ctx_partial<<<NB * NCHUNK, 512, 0, stream>>>(x, weights, partials);
    k_ctx_reduce<<<NB * ND / 256, 256, 0, stream>>>(partials, ctx);
}

// Round 6
// 195.881 us; speedup vs baseline: 1.2215x; 1.1792x over previous
//
#include <hip/hip_runtime.h>
#include <math.h>

#define NB 32
#define NT 4096
#define ND 512
#define NA 64
#define NCHUNK 16          // t-chunks for context partials
#define TCHUNK (NT / NCHUNK)

// ---------------------------------------------------------------- scores ----
// scores[b,t] = w2 . tanh(W1 @ x[b,t] + b1)
// ALL of W1 (64x512 fp32 = 128 KB) lives in LDS for the whole kernel:
// no K-chunking, no double-buffering, ONE barrier. Block = 1024 threads,
// 1 block/CU (LDS-bound), 16 waves/CU = 4/SIMD. Thread tile = 2 rows x
// 8 a-cols -> ~85 live VGPRs: fits under any allocator cap, so the R3-R5
// spill/alloca-promotion pathology is structurally impossible.
// x is streamed sequentially (16 B/row/iter): cache frontier = 1 line x
// 256 rows = 32 KB ~ L1; refetch from HBM eliminated (R4/R5 FETCH was
// 470 MB vs 268 MB ideal because 16 dq-passes thrashed L1/L2).
// W LDS layout XOR-swizzled: value (a,dq) at col dq^(a>>3); the 8 ag-lanes
// differ by 8 a-rows = 16 KB = 0 mod 128 B, so the XOR spreads them over
// 8 distinct 16-B slots -> conflict-free ds_read_b128.
#define SB 1024            // threads per block
#define RPB 256            // rows per block -> 512 blocks
#define ND4 (ND / 4)       // 128 float4 per a-row

__global__ __launch_bounds__(SB, 4) void k_scores(
    const float* __restrict__ x, const float* __restrict__ W1,
    const float* __restrict__ b1, const float* __restrict__ w2,
    float* __restrict__ scores)
{
    __shared__ float4 wl[NA * ND4];            // 128 KB

    const int tid = threadIdx.x;
    const int ag  = tid & 7;                   // a-group: cols ag*8 .. +7
    const int rg  = tid >> 3;                  // 128 row-groups x 2 rows
    const size_t row0 = (size_t)blockIdx.x * RPB + (size_t)rg * 2;

    const float4* __restrict__ x4 = reinterpret_cast<const float4*>(x);
    const float4* __restrict__ W4 = reinterpret_cast<const float4*>(W1);

    // stage ALL of W1 into LDS (swizzled), coalesced: 8 float4 per thread
#pragma unroll
    for (int r = 0; r < 8; ++r) {
        int i  = r * SB + tid;
        int a  = i >> 7;                       // / ND4
        int dq = i & (ND4 - 1);
        wl[a * ND4 + (dq ^ (a >> 3))] = W4[i];
    }
    __syncthreads();                           // the only barrier

    const float4* __restrict__ xr0 = x4 + row0 * ND4;
    const float4* __restrict__ xr1 = xr0 + ND4;
    const float4* __restrict__ wbase = wl + (size_t)ag * 8 * ND4;

    float acc[2][8];
#pragma unroll
    for (int r = 0; r < 2; ++r)
#pragma unroll
        for (int j = 0; j < 8; ++j) acc[r][j] = 0.f;

#pragma unroll 2
    for (int dq = 0; dq < ND4; ++dq) {
        float4 x0 = xr0[dq];
        float4 x1 = xr1[dq];
        const int dsw = dq ^ ag;
        float4 wv[8];
#pragma unroll
        for (int j = 0; j < 8; ++j)
            wv[j] = wbase[j * ND4 + dsw];
#pragma unroll
        for (int j = 0; j < 8; ++j) {
            acc[0][j] = fmaf(x0.x, wv[j].x, acc[0][j]);
            acc[0][j] = fmaf(x0.y, wv[j].y, acc[0][j]);
            acc[0][j] = fmaf(x0.z, wv[j].z, acc[0][j]);
            acc[0][j] = fmaf(x0.w, wv[j].w, acc[0][j]);
            acc[1][j] = fmaf(x1.x, wv[j].x, acc[1][j]);
            acc[1][j] = fmaf(x1.y, wv[j].y, acc[1][j]);
            acc[1][j] = fmaf(x1.z, wv[j].z, acc[1][j]);
            acc[1][j] = fmaf(x1.w, wv[j].w, acc[1][j]);
        }
    }

    // epilogue: p_r = sum_j w2[ag*8+j] * tanh(acc[r][j] + b1[ag*8+j])
    float b1v[8], w2v[8];
#pragma unroll
    for (int j = 0; j < 8; ++j) {
        b1v[j] = b1[ag * 8 + j];
        w2v[j] = w2[ag * 8 + j];
    }
    float p[2];
#pragma unroll
    for (int r = 0; r < 2; ++r) {
        float s = 0.f;
#pragma unroll
        for (int j = 0; j < 8; ++j)
            s += w2v[j] * tanhf(acc[r][j] + b1v[j]);
        p[r] = s;
    }
#pragma unroll
    for (int off = 1; off < 8; off <<= 1) {
        p[0] += __shfl_xor(p[0], off);
        p[1] += __shfl_xor(p[1], off);
    }
    if (ag == 0) {
        scores[row0]     = p[0];
        scores[row0 + 1] = p[1];
    }
}

// --------------------------------------------------------------- softmax ----
__global__ __launch_bounds__(256) void k_softmax(
    const float* __restrict__ scores, const int* __restrict__ mask,
    float* __restrict__ weights)
{
    __shared__ float e_lds[NT];    // 16 KB
    __shared__ float red[4];

    int b = blockIdx.x;
    const float* srow = scores + (size_t)b * NT;
    const int*   mrow = mask   + (size_t)b * NT;

    float m = -INFINITY;
    for (int i = 0; i < NT / 256; ++i) {
        int t = i * 256 + threadIdx.x;
        float s = srow[t];
        bool valid = (mrow[t] != 0);
        e_lds[t] = valid ? s : -INFINITY;
        if (valid) m = fmaxf(m, s);
    }
#pragma unroll
    for (int off = 32; off; off >>= 1) m = fmaxf(m, __shfl_xor(m, off));
    if ((threadIdx.x & 63) == 0) red[threadIdx.x >> 6] = m;
    __syncthreads();
    m = fmaxf(fmaxf(red[0], red[1]), fmaxf(red[2], red[3]));
    __syncthreads();

    float sum = 0.f;
    for (int i = 0; i < NT / 256; ++i) {
        int t = i * 256 + threadIdx.x;
        float e = expf(e_lds[t] - m);
        e_lds[t] = e;
        sum += e;
    }
#pragma unroll
    for (int off = 32; off; off >>= 1) sum += __shfl_xor(sum, off);
    if ((threadIdx.x & 63) == 0) red[threadIdx.x >> 6] = sum;
    __syncthreads();
    float total = (red[0] + red[1]) + (red[2] + red[3]);
    float inv = 1.f / total;

    for (int i = 0; i < NT / 256; ++i) {
        int t = i * 256 + threadIdx.x;
        weights[(size_t)b * NT + t] = e_lds[t] * inv;
    }
}

// ------------------------------------------------------- context partials ---
__global__ __launch_bounds__(512) void k_ctx_partial(
    const float* __restrict__ x, const float* __restrict__ weights,
    float* __restrict__ partials)
{
    int b = blockIdx.x >> 4;
    int c = blockIdx.x & (NCHUNK - 1);
    int d = threadIdx.x;

    const float* xp = x + ((size_t)b * NT + (size_t)c * TCHUNK) * ND + d;
    const float* wp = weights + (size_t)b * NT + (size_t)c * TCHUNK;

    float acc = 0.f;
#pragma unroll 4
    for (int t = 0; t < TCHUNK; ++t)
        acc = fmaf(wp[t], xp[(size_t)t * ND], acc);

    partials[(size_t)blockIdx.x * ND + d] = acc;
}

// -------------------------------------------------------- context reduce ----
__global__ __launch_bounds__(256) void k_ctx_reduce(
    const float* __restrict__ partials, float* __restrict__ ctx)
{
    int i = blockIdx.x * 256 + threadIdx.x;   // b*ND + d
    int b = i >> 9;
    int d = i & (ND - 1);
    float s = 0.f;
#pragma unroll
    for (int c = 0; c < NCHUNK; ++c)
        s += partials[((size_t)(b * NCHUNK + c)) * ND + d];
    ctx[i] = s;
}

// ------------------------------------------------------------------ launch --
extern "C" void kernel_launch(void* const* d_in, const int* in_sizes, int n_in,
                              void* d_out, int out_size, void* d_ws, size_t ws_size,
                              hipStream_t stream)
{
    const float* x    = (const float*)d_in[0];
    const int*   mask = (const int*)d_in[1];
    const float* W1   = (const float*)d_in[2];
    const float* b1   = (const float*)d_in[3];
    const float* w2   = (const float*)d_in[4];

    float* ctx     = (float*)d_out;                  // B*D
    float* weights = (float*)d_out + NB * ND;        // B*T
    float* scores   = (float*)d_ws;                  // B*T
    float* partials = (float*)d_ws + NB * NT;        // B*NCHUNK*D

    k_scores<<<(NB * NT) / RPB, SB, 0, stream>>>(x, W1, b1, w2, scores);
    k_softmax<<<NB, 256, 0, stream>>>(scores, mask, weights);
    k_ctx_partial<<<NB * NCHUNK, 512, 0, stream>>>(x, weights, partials);
    k_ctx_reduce<<<NB * ND / 256, 256, 0, stream>>>(partials, ctx);
}